// Round 1
// baseline (478.270 us; speedup 1.0000x reference)
//
#include <hip/hip_runtime.h>
#include <hip/hip_bf16.h>

typedef _Float16 half8 __attribute__((ext_vector_type(8)));
typedef _Float16 half4 __attribute__((ext_vector_type(4)));
typedef float float4_t __attribute__((ext_vector_type(4)));

// ---------------------------------------------------------------------------
// Problem constants (fixed by reference): B=8, P=4096, NC=256, M=B*P=32768
// Scales: (C,HW) = (128, 32768), (256, 8192), (512, 2048)
// ---------------------------------------------------------------------------

// Pack a (C x 256) fp32 weight into fp16 MFMA B-fragment order:
// for k-tile kt (32 rows), n-tile nt (16 cols):
//   lane = quad(k)*16 + (n&15), holds 8 halfs j=k&7 contiguous.
// packed idx = ((kt*16 + nt)*64 + lane)*8 + j
__global__ void pack_w_kernel(const float* __restrict__ w,
                              _Float16* __restrict__ wp, int total) {
    int idx = blockIdx.x * 256 + threadIdx.x;
    if (idx >= total) return;
    int k = idx >> 8, n = idx & 255;
    int kt = k >> 5, q = (k >> 3) & 3, j = k & 7;
    int nt = n >> 4, n15 = n & 15;
    int lane = q * 16 + n15;
    wp[(size_t)(((kt * 16 + nt) * 64) + lane) * 8 + j] = (_Float16)w[idx];
}

struct Params {
    const float* feat[3];
    const int*   pid[3];
    const _Float16* w1p[3];
    const float* b1[3];
    const _Float16* w2p;   // 3 scales contiguous, 65536 halfs each
    const float* b2[3];
    float* out;
};

// Block: 256 threads = 4 waves. Each block: 64 rows x 256 cols of one scale.
// Each wave: 16 rows. Layer1: acc = x @ w1 (K=C), Layer2: acc2 = relu(h) @ w2.
// h round-trips LDS within the wave only (C-layout -> A-layout).
__launch_bounds__(256, 2)
__global__ void fused_mlp_kernel(Params p) {
    // LDS: h tile 64 x 260 halfs (pad 260 -> conflict-free C-layout writes)
    //      w chunk: 2 k-steps x 16 nt x 64 lanes x 8 halfs = 32KB
    __shared__ __align__(16) _Float16 hbuf[64 * 260];
    __shared__ __align__(16) _Float16 wbuf[16384];

    int bid = blockIdx.x;
    int s = (bid >= 1024) ? 2 : (bid >= 512 ? 1 : 0);
    int mblk = bid - s * 512;
    int C  = (s == 0) ? 128 : (s == 1 ? 256 : 512);
    int HW = (s == 0) ? 32768 : (s == 1 ? 8192 : 2048);

    int tid  = threadIdx.x;
    int wv   = tid >> 6;
    int lane = tid & 63;
    int q    = (lane >> 4) & 3;
    int n15  = lane & 15;

    // Row this lane gathers (A-frag m = lane&15)
    int rowA = mblk * 64 + wv * 16 + n15;
    int b  = rowA >> 12;          // / 4096
    int jp = rowA & 4095;
    int hw = p.pid[s][b * 4096 + jp];
    const float* featb = p.feat[s] + (size_t)b * C * HW + hw;

    const _Float16* w1p = p.w1p[s];
    const float* b1 = p.b1[s];
    const _Float16* w2p = p.w2p + (size_t)s * 65536;
    const float* b2 = p.b2[s];

    float4_t acc[16];
#pragma unroll
    for (int nt = 0; nt < 16; nt++) acc[nt] = (float4_t){0.f, 0.f, 0.f, 0.f};

    // ---------------- Layer 1: x @ w1, K = C ----------------
    int nchunks = C >> 6;   // chunks of 64 K (2 MFMA k-steps)
    for (int kc = 0; kc < nchunks; kc++) {
        __syncthreads();
        {   // stage 32KB of packed w1 into LDS (256 threads x 8 x 16B)
            const float4* src = (const float4*)(w1p + (size_t)kc * 16384);
            float4* dst = (float4*)wbuf;
#pragma unroll
            for (int i = 0; i < 8; i++) dst[tid + i * 256] = src[tid + i * 256];
        }
        __syncthreads();
#pragma unroll
        for (int kk = 0; kk < 2; kk++) {
            int kt = kc * 2 + kk;
            int kbase = kt * 32 + q * 8;
            // gather A-frag: 8 strided fp32 loads, convert to fp16
            float a[8];
#pragma unroll
            for (int jj = 0; jj < 8; jj++)
                a[jj] = featb[(size_t)(kbase + jj) * HW];
            half8 afrag;
#pragma unroll
            for (int jj = 0; jj < 8; jj++) afrag[jj] = (_Float16)a[jj];
            const half8* wb = (const half8*)(wbuf + kk * 8192);
#pragma unroll
            for (int nt = 0; nt < 16; nt++) {
                half8 bfrag = wb[nt * 64 + lane];
                acc[nt] = __builtin_amdgcn_mfma_f32_16x16x32_f16(
                    afrag, bfrag, acc[nt], 0, 0, 0);
            }
        }
    }

    // ---------------- bias1 + relu -> h (fp16) in LDS ----------------
    // C-layout: row = wv*16 + q*4 + r, col = nt*16 + n15
#pragma unroll
    for (int nt = 0; nt < 16; nt++) {
        float bias = b1[nt * 16 + n15];
#pragma unroll
        for (int r = 0; r < 4; r++) {
            float v = acc[nt][r] + bias;
            v = fmaxf(v, 0.f);
            hbuf[(wv * 16 + q * 4 + r) * 260 + nt * 16 + n15] = (_Float16)v;
        }
    }
    // h rows are wave-private: same-wave RAW through LDS, no barrier needed.

#pragma unroll
    for (int nt = 0; nt < 16; nt++) acc[nt] = (float4_t){0.f, 0.f, 0.f, 0.f};

    // ---------------- Layer 2: relu(h) @ w2, K = 256 ----------------
    for (int kc = 0; kc < 4; kc++) {
        __syncthreads();   // all waves done reading previous wbuf chunk
        {
            const float4* src = (const float4*)(w2p + (size_t)kc * 16384);
            float4* dst = (float4*)wbuf;
#pragma unroll
            for (int i = 0; i < 8; i++) dst[tid + i * 256] = src[tid + i * 256];
        }
        __syncthreads();
#pragma unroll
        for (int kk = 0; kk < 2; kk++) {
            int kb = kc * 64 + kk * 32 + q * 8;
            int hoff = (wv * 16 + n15) * 260 + kb;
            half4 lo = *(const half4*)&hbuf[hoff];
            half4 hi = *(const half4*)&hbuf[hoff + 4];
            half8 afrag = __builtin_shufflevector(lo, hi, 0, 1, 2, 3, 4, 5, 6, 7);
            const half8* wb = (const half8*)(wbuf + kk * 8192);
#pragma unroll
            for (int nt = 0; nt < 16; nt++) {
                half8 bfrag = wb[nt * 64 + lane];
                acc[nt] = __builtin_amdgcn_mfma_f32_16x16x32_f16(
                    afrag, bfrag, acc[nt], 0, 0, 0);
            }
        }
    }

    // ---------------- bias2 + L2 normalize + store ----------------
    float ss[4] = {0.f, 0.f, 0.f, 0.f};
#pragma unroll
    for (int nt = 0; nt < 16; nt++) {
        float bias = b2[nt * 16 + n15];
#pragma unroll
        for (int r = 0; r < 4; r++) {
            float v = acc[nt][r] + bias;
            acc[nt][r] = v;
            ss[r] += v * v;
        }
    }
    // reduce across the 16 lanes of this quad (row group)
#pragma unroll
    for (int r = 0; r < 4; r++) {
        float t = ss[r];
        t += __shfl_xor(t, 1, 64);
        t += __shfl_xor(t, 2, 64);
        t += __shfl_xor(t, 4, 64);
        t += __shfl_xor(t, 8, 64);
        ss[r] = 1.0f / (sqrtf(t) + 1e-7f);
    }
    float* outp = p.out + (size_t)s * 32768 * 256;
    int rbase = mblk * 64 + wv * 16 + q * 4;
#pragma unroll
    for (int r = 0; r < 4; r++) {
        float inv = ss[r];
        size_t ro = (size_t)(rbase + r) * 256;
#pragma unroll
        for (int nt = 0; nt < 16; nt++)
            outp[ro + nt * 16 + n15] = acc[nt][r] * inv;
    }
}

extern "C" void kernel_launch(void* const* d_in, const int* in_sizes, int n_in,
                              void* d_out, int out_size, void* d_ws, size_t ws_size,
                              hipStream_t stream) {
    // setup_inputs dict order: per scale i: feat, pid, w1, b1, w2, b2; then num_patches
    const float* feat[3]; const int* pid[3];
    const float* w1[3]; const float* b1[3]; const float* w2[3]; const float* b2[3];
    for (int s = 0; s < 3; s++) {
        feat[s] = (const float*)d_in[6 * s + 0];
        pid[s]  = (const int*)  d_in[6 * s + 1];
        w1[s]   = (const float*)d_in[6 * s + 2];
        b1[s]   = (const float*)d_in[6 * s + 3];
        w2[s]   = (const float*)d_in[6 * s + 4];
        b2[s]   = (const float*)d_in[6 * s + 5];
    }

    // workspace layout (halfs): w1p0 | w1p1 | w1p2 | w2p x3
    _Float16* ws = (_Float16*)d_ws;
    _Float16* w1p0 = ws;                 // 128*256 = 32768
    _Float16* w1p1 = ws + 32768;         // 256*256 = 65536
    _Float16* w1p2 = ws + 98304;         // 512*256 = 131072
    _Float16* w2p  = ws + 229376;        // 3 * 65536

    pack_w_kernel<<<(32768 + 255) / 256, 256, 0, stream>>>(w1[0], w1p0, 32768);
    pack_w_kernel<<<(65536 + 255) / 256, 256, 0, stream>>>(w1[1], w1p1, 65536);
    pack_w_kernel<<<(131072 + 255) / 256, 256, 0, stream>>>(w1[2], w1p2, 131072);
    pack_w_kernel<<<(65536 + 255) / 256, 256, 0, stream>>>(w2[0], w2p, 65536);
    pack_w_kernel<<<(65536 + 255) / 256, 256, 0, stream>>>(w2[1], w2p + 65536, 65536);
    pack_w_kernel<<<(65536 + 255) / 256, 256, 0, stream>>>(w2[2], w2p + 131072, 65536);

    Params p;
    for (int s = 0; s < 3; s++) {
        p.feat[s] = feat[s]; p.pid[s] = pid[s];
        p.b1[s] = b1[s]; p.b2[s] = b2[s];
    }
    p.w1p[0] = w1p0; p.w1p[1] = w1p1; p.w1p[2] = w1p2;
    p.w2p = w2p;
    p.out = (float*)d_out;

    fused_mlp_kernel<<<1536, 256, 0, stream>>>(p);
}

// Round 2
// 399.980 us; speedup vs baseline: 1.1957x; 1.1957x over previous
//
#include <hip/hip_runtime.h>
#include <hip/hip_bf16.h>

typedef _Float16 half8 __attribute__((ext_vector_type(8)));
typedef _Float16 half4 __attribute__((ext_vector_type(4)));
typedef _Float16 half2v __attribute__((ext_vector_type(2)));
typedef float float4_t __attribute__((ext_vector_type(4)));

// ---------------------------------------------------------------------------
// B=8, P=4096, NC=256, M=32768. Scales: (C,HW) = (128,32768),(256,8192),(512,2048)
// Plan: pack weights fp16 (frag order) | transpose feat -> (B,HW,C) fp16 |
//       fused gather+MLP+L2norm with MFMA 16x16x32 f16.
// ---------------------------------------------------------------------------

// Pack (C x 256) fp32 weight into fp16 MFMA B-fragment order:
// step t = k>>5 holds 16KB: idx = ((t*16 + nt)*64 + lane)*8 + j,
// lane = quad(k)*16 + (n&15), j = k&7.
__global__ void pack_w_kernel(const float* __restrict__ w,
                              _Float16* __restrict__ wp, int total) {
    int idx = blockIdx.x * 256 + threadIdx.x;
    if (idx >= total) return;
    int k = idx >> 8, n = idx & 255;
    int kt = k >> 5, q = (k >> 3) & 3, j = k & 7;
    int nt = n >> 4, n15 = n & 15;
    int lane = q * 16 + n15;
    wp[(size_t)(((kt * 16 + nt) * 64) + lane) * 8 + j] = (_Float16)w[idx];
}

// ---------------------------------------------------------------------------
// Tiled transpose: feat (B,C,HW) fp32 -> featT (B,HW,C) fp16. 64x64 tiles.
// Phase1: coalesced float4 reads along hw, half4 store to LDS [c][hw] stride 68.
// Phase2: half2 (hw-pair) reads along c, two half8 coalesced global stores.
// ---------------------------------------------------------------------------
struct TParams {
    const float* feat[3];
    _Float16* featT[3];
};

__launch_bounds__(256, 4)
__global__ void transpose_kernel(TParams tp) {
    __shared__ __align__(16) _Float16 lds[64 * 68];
    int bid = blockIdx.x;
    int s, rem, C, HW;
    if (bid < 8192)       { s = 0; rem = bid;         C = 128; HW = 32768; }
    else if (bid < 12288) { s = 1; rem = bid - 8192;  C = 256; HW = 8192;  }
    else                  { s = 2; rem = bid - 12288; C = 512; HW = 2048;  }
    int hwTiles = HW >> 6;
    int tilesPerB = hwTiles * (C >> 6);
    int b  = rem / tilesPerB;
    int r2 = rem - b * tilesPerB;
    int ct  = r2 / hwTiles;
    int hwt = r2 - ct * hwTiles;
    int c0 = ct << 6, hw0 = hwt << 6;

    int t = threadIdx.x;
    const float* src = tp.feat[s] + ((size_t)b * C + c0) * HW + hw0;
    {   // phase 1: 64 c-rows x 64 hw floats
        int cp = t >> 4;       // 0..15
        int ch = t & 15;       // float4 chunk along hw
#pragma unroll
        for (int i = 0; i < 4; i++) {
            int c = cp + 16 * i;
            float4_t v = ((const float4_t*)(src + (size_t)c * HW))[ch];
            half4 h;
            h[0] = (_Float16)v[0]; h[1] = (_Float16)v[1];
            h[2] = (_Float16)v[2]; h[3] = (_Float16)v[3];
            *(half4*)&lds[c * 68 + ch * 4] = h;
        }
    }
    __syncthreads();
    {   // phase 2: each thread: one hw-pair x 8 c values -> two half8 stores
        int pr = t >> 3;       // 0..31 (hw pair)
        int cc = t & 7;        // c chunk of 8
        half8 o0, o1;
#pragma unroll
        for (int k = 0; k < 8; k++) {
            half2v v = *(const half2v*)&lds[(cc * 8 + k) * 68 + pr * 2];
            o0[k] = v[0]; o1[k] = v[1];
        }
        _Float16* dst = tp.featT[s];
        size_t row0 = ((size_t)b * HW + hw0 + pr * 2) * C + c0 + cc * 8;
        *(half8*)&dst[row0]     = o0;
        *(half8*)&dst[row0 + C] = o1;
    }
}

// ---------------------------------------------------------------------------
// Fused gather + 2-layer MLP + L2 normalize.
// Block = 256 thr = 4 waves; 64 rows x 256 cols. Wave owns 16 rows.
// ---------------------------------------------------------------------------
struct Params {
    const int* pid[3];
    const _Float16* featT[3];
    const _Float16* w1p[3];
    const float* b1[3];
    const _Float16* w2p;   // 3 scales x 65536 halfs
    const float* b2[3];
    float* out;
};

__device__ __forceinline__ void stage16k(const _Float16* src, _Float16* wbuf, int tid) {
    const float4_t* s4 = (const float4_t*)src;
    float4_t* d4 = (float4_t*)wbuf;
#pragma unroll
    for (int i = 0; i < 4; i++) d4[tid + i * 256] = s4[tid + i * 256];
}

template <int S>
__device__ __forceinline__ void run_scale(const Params& p, int mblk,
                                          _Float16* hbuf, _Float16* wbuf) {
    constexpr int C  = (S == 0) ? 128 : (S == 1) ? 256 : 512;
    constexpr int HW = (S == 0) ? 32768 : (S == 1) ? 8192 : 2048;
    constexpr int NSTEP = C / 32;                 // 4, 8, 16
    constexpr int NHALF = (NSTEP > 8) ? 2 : 1;    // split prefetch for S=2
    constexpr int HSTEP = NSTEP / NHALF;          // <= 8

    int tid  = threadIdx.x;
    int wv   = tid >> 6;
    int lane = tid & 63;
    int q    = (lane >> 4) & 3;
    int n15  = lane & 15;

    int rowA = mblk * 64 + wv * 16 + n15;
    int b  = rowA >> 12;
    int jp = rowA & 4095;
    int hw = p.pid[S][b * 4096 + jp];
    const _Float16* xrow = p.featT[S] + ((size_t)b * HW + hw) * C;

    float4_t acc[16];
#pragma unroll
    for (int nt = 0; nt < 16; nt++) acc[nt] = (float4_t){0.f, 0.f, 0.f, 0.f};

    const _Float16* w1p = p.w1p[S];

    // ---------------- Layer 1: K = C ----------------
#pragma unroll
    for (int h = 0; h < NHALF; h++) {
        half8 af[HSTEP];
#pragma unroll
        for (int t = 0; t < HSTEP; t++)
            af[t] = *(const half8*)(xrow + (h * HSTEP + t) * 32 + q * 8);
#pragma unroll
        for (int t = 0; t < HSTEP; t++) {
            __syncthreads();
            stage16k(w1p + (size_t)(h * HSTEP + t) * 8192, wbuf, tid);
            __syncthreads();
            const half8* wb = (const half8*)wbuf;
#pragma unroll
            for (int nt = 0; nt < 16; nt++)
                acc[nt] = __builtin_amdgcn_mfma_f32_16x16x32_f16(
                    af[t], wb[nt * 64 + lane], acc[nt], 0, 0, 0);
        }
    }

    // ---------------- bias1 + relu -> hbuf fp16 ----------------
    const float* b1 = p.b1[S];
#pragma unroll
    for (int nt = 0; nt < 16; nt++) {
        float bias = b1[nt * 16 + n15];
#pragma unroll
        for (int r = 0; r < 4; r++) {
            float v = fmaxf(acc[nt][r] + bias, 0.f);
            hbuf[(wv * 16 + q * 4 + r) * 260 + nt * 16 + n15] = (_Float16)v;
        }
    }
    // h rows are wave-private: same-wave LDS RAW, no barrier needed.

#pragma unroll
    for (int nt = 0; nt < 16; nt++) acc[nt] = (float4_t){0.f, 0.f, 0.f, 0.f};

    // ---------------- Layer 2: K = 256 ----------------
    const _Float16* w2p = p.w2p + (size_t)S * 65536;
#pragma unroll
    for (int t = 0; t < 8; t++) {
        __syncthreads();
        stage16k(w2p + (size_t)t * 8192, wbuf, tid);
        __syncthreads();
        int kb = t * 32 + q * 8;
        int hoff = (wv * 16 + n15) * 260 + kb;
        half4 lo = *(const half4*)&hbuf[hoff];
        half4 hi = *(const half4*)&hbuf[hoff + 4];
        half8 afr = __builtin_shufflevector(lo, hi, 0, 1, 2, 3, 4, 5, 6, 7);
        const half8* wb = (const half8*)wbuf;
#pragma unroll
        for (int nt = 0; nt < 16; nt++)
            acc[nt] = __builtin_amdgcn_mfma_f32_16x16x32_f16(
                afr, wb[nt * 64 + lane], acc[nt], 0, 0, 0);
    }

    // ---------------- bias2 + L2 norm + store ----------------
    const float* b2 = p.b2[S];
    float ss[4] = {0.f, 0.f, 0.f, 0.f};
#pragma unroll
    for (int nt = 0; nt < 16; nt++) {
        float bias = b2[nt * 16 + n15];
#pragma unroll
        for (int r = 0; r < 4; r++) {
            float v = acc[nt][r] + bias;
            acc[nt][r] = v;
            ss[r] += v * v;
        }
    }
#pragma unroll
    for (int r = 0; r < 4; r++) {
        float t2 = ss[r];
        t2 += __shfl_xor(t2, 1, 64);
        t2 += __shfl_xor(t2, 2, 64);
        t2 += __shfl_xor(t2, 4, 64);
        t2 += __shfl_xor(t2, 8, 64);
        ss[r] = 1.0f / (sqrtf(t2) + 1e-7f);
    }
    float* outp = p.out + (size_t)S * 32768 * 256;
    int rbase = mblk * 64 + wv * 16 + q * 4;
#pragma unroll
    for (int r = 0; r < 4; r++) {
        float inv = ss[r];
        size_t ro = (size_t)(rbase + r) * 256;
#pragma unroll
        for (int nt = 0; nt < 16; nt++)
            outp[ro + nt * 16 + n15] = acc[nt][r] * inv;
    }
}

__launch_bounds__(256, 3)
__global__ void fused_mlp_kernel(Params p) {
    __shared__ __align__(16) _Float16 hbuf[64 * 260];  // 33280 B
    __shared__ __align__(16) _Float16 wbuf[8192];      // 16384 B
    int bid  = blockIdx.x;
    int s    = bid % 3;          // interleave scales across CUs
    int mblk = bid / 3;
    if (s == 0)      run_scale<0>(p, mblk, hbuf, wbuf);
    else if (s == 1) run_scale<1>(p, mblk, hbuf, wbuf);
    else             run_scale<2>(p, mblk, hbuf, wbuf);
}

extern "C" void kernel_launch(void* const* d_in, const int* in_sizes, int n_in,
                              void* d_out, int out_size, void* d_ws, size_t ws_size,
                              hipStream_t stream) {
    const float* feat[3]; const int* pid[3];
    const float* w1[3]; const float* b1[3]; const float* w2[3]; const float* b2[3];
    for (int s = 0; s < 3; s++) {
        feat[s] = (const float*)d_in[6 * s + 0];
        pid[s]  = (const int*)  d_in[6 * s + 1];
        w1[s]   = (const float*)d_in[6 * s + 2];
        b1[s]   = (const float*)d_in[6 * s + 3];
        w2[s]   = (const float*)d_in[6 * s + 4];
        b2[s]   = (const float*)d_in[6 * s + 5];
    }

    // ws layout (halfs): w1p0 | w1p1 | w1p2 | w2p(x3) | featT0 | featT1 | featT2
    _Float16* ws = (_Float16*)d_ws;
    _Float16* w1p0   = ws;                    // 32768
    _Float16* w1p1   = ws + 32768;            // 65536
    _Float16* w1p2   = ws + 98304;            // 131072
    _Float16* w2p    = ws + 229376;           // 3*65536 = 196608
    _Float16* featT0 = ws + 425984;           // 8*32768*128 = 33554432
    _Float16* featT1 = ws + 33980416;         // 8*8192*256  = 16777216
    _Float16* featT2 = ws + 50757632;         // 8*2048*512  = 8388608
    // total: 59146240 halfs = 118.3 MB

    pack_w_kernel<<<128, 256, 0, stream>>>(w1[0], w1p0, 32768);
    pack_w_kernel<<<256, 256, 0, stream>>>(w1[1], w1p1, 65536);
    pack_w_kernel<<<512, 256, 0, stream>>>(w1[2], w1p2, 131072);
    pack_w_kernel<<<256, 256, 0, stream>>>(w2[0], w2p, 65536);
    pack_w_kernel<<<256, 256, 0, stream>>>(w2[1], w2p + 65536, 65536);
    pack_w_kernel<<<256, 256, 0, stream>>>(w2[2], w2p + 131072, 65536);

    TParams tp;
    tp.feat[0] = feat[0]; tp.feat[1] = feat[1]; tp.feat[2] = feat[2];
    tp.featT[0] = featT0; tp.featT[1] = featT1; tp.featT[2] = featT2;
    transpose_kernel<<<14336, 256, 0, stream>>>(tp);

    Params p;
    for (int s = 0; s < 3; s++) {
        p.pid[s] = pid[s];
        p.b1[s] = b1[s]; p.b2[s] = b2[s];
    }
    p.featT[0] = featT0; p.featT[1] = featT1; p.featT[2] = featT2;
    p.w1p[0] = w1p0; p.w1p[1] = w1p1; p.w1p[2] = w1p2;
    p.w2p = w2p;
    p.out = (float*)d_out;

    fused_mlp_kernel<<<1536, 256, 0, stream>>>(p);
}